// Round 2
// baseline (12012.026 us; speedup 1.0000x reference)
//
#include <hip/hip_runtime.h>
#include <math.h>

#define NNODE 50000
#define NEDGE 800000
#define ENC_NEGINF 0x007FFFFFu

// monotone float->uint encoding for atomicMax on floats (handles negatives)
__device__ __forceinline__ unsigned encf(float f) {
    unsigned b = __float_as_uint(f);
    return (b & 0x80000000u) ? ~b : (b | 0x80000000u);
}
__device__ __forceinline__ float decf(unsigned u) {
    unsigned b = (u >> 31) ? (u ^ 0x80000000u) : ~u;
    return __uint_as_float(b);
}

__device__ __forceinline__ float wsum64(float v) {
    #pragma unroll
    for (int m = 32; m >= 1; m >>= 1) v += __shfl_xor(v, m, 64);
    return v;
}

__device__ __forceinline__ float gelu_exact(float x) {
    return 0.5f * x * (1.0f + erff(x * 0.70710678118654752f));
}

// ---------------- utility fill ----------------
__global__ void fill_u32(unsigned* __restrict__ p, unsigned v, int n) {
    int i = blockIdx.x * blockDim.x + threadIdx.x;
    if (i < n) p[i] = v;
}

// ---------------- layer 1: node transforms (x[N,64] -> xl,xr [N,128]) ----------------
__global__ __launch_bounds__(256) void node_xform1(const float* __restrict__ x,
                                                   const float* __restrict__ wl,
                                                   const float* __restrict__ wr,
                                                   float* __restrict__ xl,
                                                   float* __restrict__ xr) {
    __shared__ float xrow[64];
    int n = blockIdx.x;
    int t = threadIdx.x;
    if (t < 64) xrow[t] = x[(size_t)n * 64 + t];
    __syncthreads();
    const float* w;
    float* o;
    int c;
    if (t < 128) { w = wl; c = t; o = xl; }
    else         { w = wr; c = t - 128; o = xr; }
    float acc = 0.f;
    #pragma unroll 8
    for (int i = 0; i < 64; ++i) acc += xrow[i] * w[i * 128 + c];
    o[(size_t)n * 128 + c] = acc;
}

// ---------------- layer 2: node transforms (h1[N,128] -> xl2,xr2 [N,128]) ----------------
__global__ __launch_bounds__(256) void node_xform2(const float* __restrict__ h1,
                                                   const float* __restrict__ wl,
                                                   const float* __restrict__ wr,
                                                   float* __restrict__ xl,
                                                   float* __restrict__ xr) {
    __shared__ float hrow[128];
    int n = blockIdx.x;
    int t = threadIdx.x;
    if (t < 128) hrow[t] = h1[(size_t)n * 128 + t];
    __syncthreads();
    const float* w;
    float* o;
    int c;
    if (t < 128) { w = wl; c = t; o = xl; }
    else         { w = wr; c = t - 128; o = xr; }
    float acc = 0.f;
    #pragma unroll 8
    for (int i = 0; i < 128; ++i) acc += hrow[i] * w[i * 128 + c];
    o[(size_t)n * 128 + c] = acc;
}

// ---------------- layer 1 edge kernels (H=8, C=16) ----------------
__global__ __launch_bounds__(256) void edge_score1(const int* __restrict__ ei,
                                                   const float* __restrict__ ea,
                                                   const float* __restrict__ xl,
                                                   const float* __restrict__ xr,
                                                   const float* __restrict__ w1e,
                                                   const float* __restrict__ att1,
                                                   float* __restrict__ score,
                                                   unsigned* __restrict__ smax) {
    __shared__ float we[128], at[128];
    int t = threadIdx.x;
    if (t < 128) { we[t] = w1e[t]; at[t] = att1[t]; }
    __syncthreads();
    int e = blockIdx.x * 256 + t;
    if (e >= NEDGE) return;
    int s = ei[e], d = ei[NEDGE + e];
    float a = ea[e];
    const float4* xs = (const float4*)(xl + (size_t)s * 128);
    const float4* xd = (const float4*)(xr + (size_t)d * 128);
    #pragma unroll
    for (int h = 0; h < 8; ++h) {
        float sc = 0.f;
        #pragma unroll
        for (int q = 0; q < 4; ++q) {
            float4 u = xs[h * 4 + q];
            float4 v = xd[h * 4 + q];
            int b = h * 16 + q * 4;
            float z0 = u.x + v.x + a * we[b + 0]; z0 = z0 > 0.f ? z0 : 0.2f * z0;
            float z1 = u.y + v.y + a * we[b + 1]; z1 = z1 > 0.f ? z1 : 0.2f * z1;
            float z2 = u.z + v.z + a * we[b + 2]; z2 = z2 > 0.f ? z2 : 0.2f * z2;
            float z3 = u.w + v.w + a * we[b + 3]; z3 = z3 > 0.f ? z3 : 0.2f * z3;
            sc += z0 * at[b + 0] + z1 * at[b + 1] + z2 * at[b + 2] + z3 * at[b + 3];
        }
        score[(size_t)e * 8 + h] = sc;
        atomicMax(smax + (size_t)d * 8 + h, encf(sc));
    }
}

__global__ __launch_bounds__(256) void edge_exp1(const int* __restrict__ ei,
                                                 const unsigned* __restrict__ smax,
                                                 float* __restrict__ score,
                                                 float* __restrict__ denom) {
    int e = blockIdx.x * 256 + threadIdx.x;
    if (e >= NEDGE) return;
    int d = ei[NEDGE + e];
    #pragma unroll
    for (int h = 0; h < 8; ++h) {
        float m = decf(smax[(size_t)d * 8 + h]);
        float v = expf(score[(size_t)e * 8 + h] - m);
        score[(size_t)e * 8 + h] = v;
        atomicAdd(denom + (size_t)d * 8 + h, v);
    }
}

__global__ __launch_bounds__(256) void edge_aggr1(const int* __restrict__ ei,
                                                  const float* __restrict__ score,
                                                  const float* __restrict__ denom,
                                                  const float* __restrict__ xl,
                                                  float* __restrict__ acc) {
    int e = blockIdx.x * 256 + threadIdx.x;
    if (e >= NEDGE) return;
    int s = ei[e], d = ei[NEDGE + e];
    const float4* xs = (const float4*)(xl + (size_t)s * 128);
    float* ad = acc + (size_t)d * 128;
    #pragma unroll
    for (int h = 0; h < 8; ++h) {
        float alpha = score[(size_t)e * 8 + h] / (denom[(size_t)d * 8 + h] + 1e-16f);
        #pragma unroll
        for (int q = 0; q < 4; ++q) {
            float4 u = xs[h * 4 + q];
            int b = h * 16 + q * 4;
            atomicAdd(ad + b + 0, u.x * alpha);
            atomicAdd(ad + b + 1, u.y * alpha);
            atomicAdd(ad + b + 2, u.z * alpha);
            atomicAdd(ad + b + 3, u.w * alpha);
        }
    }
}

__global__ void finalize1(const float* __restrict__ acc,
                          const float* __restrict__ b1,
                          float* __restrict__ h1) {
    int i = blockIdx.x * blockDim.x + threadIdx.x;
    if (i >= NNODE * 128) return;
    float v = acc[i] + b1[i & 127];
    h1[i] = v > 0.f ? v : 0.f;
}

// ---------------- layer 2 edge kernels (H=2, C=64) ----------------
__global__ __launch_bounds__(256) void edge_score2(const int* __restrict__ ei,
                                                   const float* __restrict__ ea,
                                                   const float* __restrict__ xl,
                                                   const float* __restrict__ xr,
                                                   const float* __restrict__ w2e,
                                                   const float* __restrict__ att2,
                                                   float* __restrict__ score,
                                                   unsigned* __restrict__ smax) {
    __shared__ float we[128], at[128];
    int t = threadIdx.x;
    if (t < 128) { we[t] = w2e[t]; at[t] = att2[t]; }
    __syncthreads();
    int e = blockIdx.x * 256 + t;
    if (e >= NEDGE) return;
    int s = ei[e], d = ei[NEDGE + e];
    float a = ea[e];
    const float4* xs = (const float4*)(xl + (size_t)s * 128);
    const float4* xd = (const float4*)(xr + (size_t)d * 128);
    #pragma unroll
    for (int h = 0; h < 2; ++h) {
        float sc = 0.f;
        #pragma unroll
        for (int q = 0; q < 16; ++q) {
            float4 u = xs[h * 16 + q];
            float4 v = xd[h * 16 + q];
            int b = h * 64 + q * 4;
            float z0 = u.x + v.x + a * we[b + 0]; z0 = z0 > 0.f ? z0 : 0.2f * z0;
            float z1 = u.y + v.y + a * we[b + 1]; z1 = z1 > 0.f ? z1 : 0.2f * z1;
            float z2 = u.z + v.z + a * we[b + 2]; z2 = z2 > 0.f ? z2 : 0.2f * z2;
            float z3 = u.w + v.w + a * we[b + 3]; z3 = z3 > 0.f ? z3 : 0.2f * z3;
            sc += z0 * at[b + 0] + z1 * at[b + 1] + z2 * at[b + 2] + z3 * at[b + 3];
        }
        score[(size_t)e * 2 + h] = sc;
        atomicMax(smax + (size_t)d * 2 + h, encf(sc));
    }
}

__global__ __launch_bounds__(256) void edge_exp2(const int* __restrict__ ei,
                                                 const unsigned* __restrict__ smax,
                                                 float* __restrict__ score,
                                                 float* __restrict__ denom) {
    int e = blockIdx.x * 256 + threadIdx.x;
    if (e >= NEDGE) return;
    int d = ei[NEDGE + e];
    #pragma unroll
    for (int h = 0; h < 2; ++h) {
        float m = decf(smax[(size_t)d * 2 + h]);
        float v = expf(score[(size_t)e * 2 + h] - m);
        score[(size_t)e * 2 + h] = v;
        atomicAdd(denom + (size_t)d * 2 + h, v);
    }
}

__global__ __launch_bounds__(256) void edge_aggr2(const int* __restrict__ ei,
                                                  const float* __restrict__ score,
                                                  const float* __restrict__ denom,
                                                  const float* __restrict__ xl,
                                                  float* __restrict__ acc) {
    int e = blockIdx.x * 256 + threadIdx.x;
    if (e >= NEDGE) return;
    int s = ei[e], d = ei[NEDGE + e];
    const float4* xs = (const float4*)(xl + (size_t)s * 128);
    float* ad = acc + (size_t)d * 128;
    #pragma unroll
    for (int h = 0; h < 2; ++h) {
        float alpha = score[(size_t)e * 2 + h] / (denom[(size_t)d * 2 + h] + 1e-16f);
        #pragma unroll
        for (int q = 0; q < 16; ++q) {
            float4 u = xs[h * 16 + q];
            int b = h * 64 + q * 4;
            atomicAdd(ad + b + 0, u.x * alpha);
            atomicAdd(ad + b + 1, u.y * alpha);
            atomicAdd(ad + b + 2, u.z * alpha);
            atomicAdd(ad + b + 3, u.w * alpha);
        }
    }
}

__global__ void finalize2(const float* __restrict__ acc,
                          const float* __restrict__ b2,
                          float* __restrict__ h2) {
    int i = blockIdx.x * blockDim.x + threadIdx.x;
    if (i >= NNODE * 64) return;
    int n = i >> 6, c = i & 63;
    float v = 0.5f * (acc[(size_t)n * 128 + c] + acc[(size_t)n * 128 + 64 + c]) + b2[c];
    h2[i] = v > 0.f ? v : 0.f;
}

// ---------------- classifier: one wave (64 lanes) per node ----------------
__global__ __launch_bounds__(256) void classifier(const float* __restrict__ h2,
                                                  const float* __restrict__ wc,
                                                  const float* __restrict__ bc,
                                                  const float* __restrict__ lng,
                                                  const float* __restrict__ lnb,
                                                  const float* __restrict__ wr,
                                                  const float* __restrict__ br,
                                                  const float* __restrict__ lrg,
                                                  const float* __restrict__ lrb,
                                                  float* __restrict__ out) {
    __shared__ float rowA[4][64];
    __shared__ float rowB[4][64];
    int t = threadIdx.x;
    int wv = t >> 6, ln = t & 63;
    int n = blockIdx.x * 4 + wv;   // NNODE divisible by 4
    rowA[wv][ln] = h2[(size_t)n * 64 + ln];
    __syncthreads();
    float acc = bc[ln];
    #pragma unroll 8
    for (int i = 0; i < 64; ++i) acc += rowA[wv][i] * wc[i * 64 + ln];
    float mu = wsum64(acc) * (1.f / 64.f);
    float dv = acc - mu;
    float var = wsum64(dv * dv) * (1.f / 64.f);
    float y = dv * rsqrtf(var + 1e-5f) * lng[ln] + lnb[ln];
    float g1 = gelu_exact(y);
    rowB[wv][ln] = g1;
    __syncthreads();
    float acc2 = br[ln];
    #pragma unroll 8
    for (int i = 0; i < 64; ++i) acc2 += rowB[wv][i] * wr[i * 64 + ln];
    float mu2 = wsum64(acc2) * (1.f / 64.f);
    float dv2 = acc2 - mu2;
    float var2 = wsum64(dv2 * dv2) * (1.f / 64.f);
    float y2 = dv2 * rsqrtf(var2 + 1e-5f) * lrg[ln] + lrb[ln];
    float g2 = gelu_exact(y2);
    out[(size_t)n * 64 + ln] = g1 + g2;
}

extern "C" void kernel_launch(void* const* d_in, const int* in_sizes, int n_in,
                              void* d_out, int out_size, void* d_ws, size_t ws_size,
                              hipStream_t stream) {
    const float* x    = (const float*)d_in[0];
    const int*   ei   = (const int*)d_in[1];
    const float* ea   = (const float*)d_in[2];
    const float* w1l  = (const float*)d_in[3];
    const float* w1r  = (const float*)d_in[4];
    const float* w1e  = (const float*)d_in[5];
    const float* att1 = (const float*)d_in[6];
    const float* b1   = (const float*)d_in[7];
    const float* w2l  = (const float*)d_in[8];
    const float* w2r  = (const float*)d_in[9];
    const float* w2e  = (const float*)d_in[10];
    const float* att2 = (const float*)d_in[11];
    const float* b2   = (const float*)d_in[12];
    const float* wc   = (const float*)d_in[13];
    const float* bc   = (const float*)d_in[14];
    const float* lng  = (const float*)d_in[15];
    const float* lnb  = (const float*)d_in[16];
    const float* wr   = (const float*)d_in[17];
    const float* br   = (const float*)d_in[18];
    const float* lrg  = (const float*)d_in[19];
    const float* lrb  = (const float*)d_in[20];

    float* ws = (float*)d_ws;
    const size_t N128 = (size_t)NNODE * 128;
    float*    xl    = ws;
    float*    xr    = xl + N128;
    float*    h1    = xr + N128;                  // reused as h2 (N*64) in stage 2
    float*    acc   = h1 + N128;
    float*    score = acc + N128;                 // E*8 floats
    unsigned* smax  = (unsigned*)(score + (size_t)NEDGE * 8);  // N*8
    float*    denom = (float*)smax + (size_t)NNODE * 8;        // N*8

    const int EB = NEDGE / 256;  // 3125

    // ---- layer 1 ----
    node_xform1<<<NNODE, 256, 0, stream>>>(x, w1l, w1r, xl, xr);
    fill_u32<<<(NNODE * 8 + 255) / 256, 256, 0, stream>>>(smax, ENC_NEGINF, NNODE * 8);
    fill_u32<<<(NNODE * 8 + 255) / 256, 256, 0, stream>>>((unsigned*)denom, 0u, NNODE * 8);
    fill_u32<<<(NNODE * 128 + 255) / 256, 256, 0, stream>>>((unsigned*)acc, 0u, NNODE * 128);
    edge_score1<<<EB, 256, 0, stream>>>(ei, ea, xl, xr, w1e, att1, score, smax);
    edge_exp1<<<EB, 256, 0, stream>>>(ei, smax, score, denom);
    edge_aggr1<<<EB, 256, 0, stream>>>(ei, score, denom, xl, acc);
    finalize1<<<(NNODE * 128 + 255) / 256, 256, 0, stream>>>(acc, b1, h1);

    // ---- layer 2 (reuse xl/xr/score/smax/denom/acc) ----
    node_xform2<<<NNODE, 256, 0, stream>>>(h1, w2l, w2r, xl, xr);
    fill_u32<<<(NNODE * 2 + 255) / 256, 256, 0, stream>>>(smax, ENC_NEGINF, NNODE * 2);
    fill_u32<<<(NNODE * 2 + 255) / 256, 256, 0, stream>>>((unsigned*)denom, 0u, NNODE * 2);
    fill_u32<<<(NNODE * 128 + 255) / 256, 256, 0, stream>>>((unsigned*)acc, 0u, NNODE * 128);
    edge_score2<<<EB, 256, 0, stream>>>(ei, ea, xl, xr, w2e, att2, score, smax);
    edge_exp2<<<EB, 256, 0, stream>>>(ei, smax, score, denom);
    edge_aggr2<<<EB, 256, 0, stream>>>(ei, score, denom, xl, acc);
    // h2 aliases h1 (h1 dead after node_xform2)
    finalize2<<<(NNODE * 64 + 255) / 256, 256, 0, stream>>>(acc, b2, h1);

    // ---- classifier ----
    classifier<<<NNODE / 4, 256, 0, stream>>>(h1, wc, bc, lng, lnb, wr, br, lrg, lrb,
                                              (float*)d_out);
}

// Round 3
// 486.084 us; speedup vs baseline: 24.7119x; 24.7119x over previous
//
#include <hip/hip_runtime.h>
#include <math.h>

#define NNODE 50000
#define NEDGE 800000
#define NBLK_SCAN 196   // ceil(50000/256)

__device__ __forceinline__ float wsum64(float v) {
    #pragma unroll
    for (int m = 32; m >= 1; m >>= 1) v += __shfl_xor(v, m, 64);
    return v;
}

__device__ __forceinline__ float gelu_exact(float x) {
    return 0.5f * x * (1.0f + erff(x * 0.70710678118654752f));
}

__device__ __forceinline__ float lrelu(float z) { return z > 0.f ? z : 0.2f * z; }

// ---------------- utility ----------------
__global__ void fill_u32(unsigned* __restrict__ p, unsigned v, int n) {
    int i = blockIdx.x * blockDim.x + threadIdx.x;
    if (i < n) p[i] = v;
}

// ---------------- CSR build ----------------
__global__ __launch_bounds__(256) void build_deg(const int* __restrict__ ei, int* __restrict__ deg) {
    int e = blockIdx.x * 256 + threadIdx.x;
    if (e >= NEDGE) return;
    atomicAdd(&deg[ei[NEDGE + e]], 1);
}

// block-level exclusive scan (Hillis-Steele), emits block sums
__global__ __launch_bounds__(256) void scan1(const int* __restrict__ deg,
                                             int* __restrict__ partial,
                                             int* __restrict__ bsum) {
    __shared__ int tmp[256];
    int t = threadIdx.x;
    int gid = blockIdx.x * 256 + t;
    int v = (gid < NNODE) ? deg[gid] : 0;
    tmp[t] = v;
    __syncthreads();
    #pragma unroll
    for (int off = 1; off < 256; off <<= 1) {
        int u = (t >= off) ? tmp[t - off] : 0;
        __syncthreads();
        tmp[t] += u;
        __syncthreads();
    }
    if (gid < NNODE) partial[gid] = tmp[t] - v;   // exclusive
    if (t == 255) bsum[blockIdx.x] = tmp[255];
}

__global__ __launch_bounds__(256) void scan2(int* __restrict__ bsum, int* __restrict__ boff) {
    __shared__ int tmp[256];
    int t = threadIdx.x;
    int v = (t < NBLK_SCAN) ? bsum[t] : 0;
    tmp[t] = v;
    __syncthreads();
    #pragma unroll
    for (int off = 1; off < 256; off <<= 1) {
        int u = (t >= off) ? tmp[t - off] : 0;
        __syncthreads();
        tmp[t] += u;
        __syncthreads();
    }
    if (t < NBLK_SCAN) boff[t] = tmp[t] - v;      // exclusive
}

__global__ __launch_bounds__(256) void scan3(const int* __restrict__ partial,
                                             const int* __restrict__ boff,
                                             int* __restrict__ base,
                                             int* __restrict__ cursor) {
    int gid = blockIdx.x * 256 + threadIdx.x;
    if (gid < NNODE) {
        int b = partial[gid] + boff[blockIdx.x];
        base[gid] = b;
        cursor[gid] = b;
    }
    if (gid == 0) base[NNODE] = NEDGE;
}

__global__ __launch_bounds__(256) void scatter_edges(const int* __restrict__ ei,
                                                     const float* __restrict__ ea,
                                                     int* __restrict__ cursor,
                                                     int* __restrict__ srcS,
                                                     float* __restrict__ eaS) {
    int e = blockIdx.x * 256 + threadIdx.x;
    if (e >= NEDGE) return;
    int d = ei[NEDGE + e];
    int i = atomicAdd(&cursor[d], 1);
    srcS[i] = ei[e];
    eaS[i] = ea[e];
}

// ---------------- node transforms: 8 nodes/block for weight reuse ----------------
__global__ __launch_bounds__(256) void node_xform1(const float* __restrict__ x,
                                                   const float* __restrict__ wl,
                                                   const float* __restrict__ wr,
                                                   float* __restrict__ xl,
                                                   float* __restrict__ xr) {
    __shared__ float xrow[8][64];
    int t = threadIdx.x;
    int n0 = blockIdx.x * 8;
    for (int k = t; k < 8 * 64; k += 256) xrow[k >> 6][k & 63] = x[(size_t)n0 * 64 + k];
    __syncthreads();
    const float* w;
    float* o;
    int c;
    if (t < 128) { w = wl; c = t; o = xl; }
    else         { w = wr; c = t - 128; o = xr; }
    float acc[8] = {0.f, 0.f, 0.f, 0.f, 0.f, 0.f, 0.f, 0.f};
    for (int i = 0; i < 64; ++i) {
        float wv = w[i * 128 + c];
        #pragma unroll
        for (int k = 0; k < 8; ++k) acc[k] += xrow[k][i] * wv;
    }
    #pragma unroll
    for (int k = 0; k < 8; ++k) o[(size_t)(n0 + k) * 128 + c] = acc[k];
}

__global__ __launch_bounds__(256) void node_xform2(const float* __restrict__ h1,
                                                   const float* __restrict__ wl,
                                                   const float* __restrict__ wr,
                                                   float* __restrict__ xl,
                                                   float* __restrict__ xr) {
    __shared__ float hrow[8][128];
    int t = threadIdx.x;
    int n0 = blockIdx.x * 8;
    for (int k = t; k < 8 * 128; k += 256) hrow[k >> 7][k & 127] = h1[(size_t)n0 * 128 + k];
    __syncthreads();
    const float* w;
    float* o;
    int c;
    if (t < 128) { w = wl; c = t; o = xl; }
    else         { w = wr; c = t - 128; o = xr; }
    float acc[8] = {0.f, 0.f, 0.f, 0.f, 0.f, 0.f, 0.f, 0.f};
    for (int i = 0; i < 128; ++i) {
        float wv = w[i * 128 + c];
        #pragma unroll
        for (int k = 0; k < 8; ++k) acc[k] += hrow[k][i] * wv;
    }
    #pragma unroll
    for (int k = 0; k < 8; ++k) o[(size_t)(n0 + k) * 128 + c] = acc[k];
}

// ---------------- fused online-softmax GAT layer 1 (H=8, C=16) ----------------
// one wave per node; lane owns 2 channels; 8-lane groups = one head
__global__ __launch_bounds__(256) void fused1(const int* __restrict__ base,
                                              const int* __restrict__ srcS,
                                              const float* __restrict__ eaS,
                                              const float* __restrict__ xl,
                                              const float* __restrict__ xr,
                                              const float* __restrict__ w1e,
                                              const float* __restrict__ att1,
                                              const float* __restrict__ b1,
                                              float* __restrict__ h1) {
    int t = threadIdx.x;
    int wv = t >> 6, ln = t & 63;
    int n = blockIdx.x * 4 + wv;
    int ch = 2 * ln;
    float xr0 = xr[(size_t)n * 128 + ch], xr1 = xr[(size_t)n * 128 + ch + 1];
    float we0 = w1e[ch], we1 = w1e[ch + 1];
    float at0 = att1[ch], at1 = att1[ch + 1];
    int i0 = base[n], i1 = base[n + 1];
    float m = -INFINITY, den = 0.f, o0 = 0.f, o1 = 0.f;
    for (int i = i0; i < i1; ++i) {
        int s = srcS[i];
        float a = eaS[i];
        const float* xs = xl + (size_t)s * 128;
        float x0 = xs[ch], x1 = xs[ch + 1];
        float part = lrelu(x0 + xr0 + a * we0) * at0 + lrelu(x1 + xr1 + a * we1) * at1;
        part += __shfl_xor(part, 1, 64);
        part += __shfl_xor(part, 2, 64);
        part += __shfl_xor(part, 4, 64);   // score for this head, same across 8-lane group
        if (part <= m) {
            float p = __expf(part - m);
            den += p; o0 += p * x0; o1 += p * x1;
        } else {
            float r = __expf(m - part);
            den = den * r + 1.f; o0 = o0 * r + x0; o1 = o1 * r + x1;
            m = part;
        }
    }
    float inv = 1.f / (den + 1e-16f);
    float v0 = o0 * inv + b1[ch];
    float v1 = o1 * inv + b1[ch + 1];
    h1[(size_t)n * 128 + ch]     = v0 > 0.f ? v0 : 0.f;
    h1[(size_t)n * 128 + ch + 1] = v1 > 0.f ? v1 : 0.f;
}

// ---------------- fused online-softmax GAT layer 2 (H=2, C=64, mean) ----------------
__global__ __launch_bounds__(256) void fused2(const int* __restrict__ base,
                                              const int* __restrict__ srcS,
                                              const float* __restrict__ eaS,
                                              const float* __restrict__ xl,
                                              const float* __restrict__ xr,
                                              const float* __restrict__ w2e,
                                              const float* __restrict__ att2,
                                              const float* __restrict__ b2,
                                              float* __restrict__ h2) {
    int t = threadIdx.x;
    int wv = t >> 6, ln = t & 63;
    int n = blockIdx.x * 4 + wv;
    int ch = 2 * ln;
    float xr0 = xr[(size_t)n * 128 + ch], xr1 = xr[(size_t)n * 128 + ch + 1];
    float we0 = w2e[ch], we1 = w2e[ch + 1];
    float at0 = att2[ch], at1 = att2[ch + 1];
    int i0 = base[n], i1 = base[n + 1];
    float m = -INFINITY, den = 0.f, o0 = 0.f, o1 = 0.f;
    for (int i = i0; i < i1; ++i) {
        int s = srcS[i];
        float a = eaS[i];
        const float* xs = xl + (size_t)s * 128;
        float x0 = xs[ch], x1 = xs[ch + 1];
        float part = lrelu(x0 + xr0 + a * we0) * at0 + lrelu(x1 + xr1 + a * we1) * at1;
        part += __shfl_xor(part, 1, 64);
        part += __shfl_xor(part, 2, 64);
        part += __shfl_xor(part, 4, 64);
        part += __shfl_xor(part, 8, 64);
        part += __shfl_xor(part, 16, 64);  // score for this head (32-lane group)
        if (part <= m) {
            float p = __expf(part - m);
            den += p; o0 += p * x0; o1 += p * x1;
        } else {
            float r = __expf(m - part);
            den = den * r + 1.f; o0 = o0 * r + x0; o1 = o1 * r + x1;
            m = part;
        }
    }
    float inv = 1.f / (den + 1e-16f);
    float v0 = o0 * inv, v1 = o1 * inv;
    float u0 = __shfl_xor(v0, 32, 64);
    float u1 = __shfl_xor(v1, 32, 64);
    if (ln < 32) {
        int c = 2 * ln;
        float r0 = 0.5f * (v0 + u0) + b2[c];
        float r1 = 0.5f * (v1 + u1) + b2[c + 1];
        h2[(size_t)n * 64 + c]     = r0 > 0.f ? r0 : 0.f;
        h2[(size_t)n * 64 + c + 1] = r1 > 0.f ? r1 : 0.f;
    }
}

// ---------------- classifier: one wave (64 lanes) per node ----------------
__global__ __launch_bounds__(256) void classifier(const float* __restrict__ h2,
                                                  const float* __restrict__ wc,
                                                  const float* __restrict__ bc,
                                                  const float* __restrict__ lng,
                                                  const float* __restrict__ lnb,
                                                  const float* __restrict__ wr,
                                                  const float* __restrict__ br,
                                                  const float* __restrict__ lrg,
                                                  const float* __restrict__ lrb,
                                                  float* __restrict__ out) {
    __shared__ float rowA[4][64];
    __shared__ float rowB[4][64];
    int t = threadIdx.x;
    int wv = t >> 6, ln = t & 63;
    int n = blockIdx.x * 4 + wv;
    rowA[wv][ln] = h2[(size_t)n * 64 + ln];
    __syncthreads();
    float acc = bc[ln];
    #pragma unroll 8
    for (int i = 0; i < 64; ++i) acc += rowA[wv][i] * wc[i * 64 + ln];
    float mu = wsum64(acc) * (1.f / 64.f);
    float dv = acc - mu;
    float var = wsum64(dv * dv) * (1.f / 64.f);
    float y = dv * rsqrtf(var + 1e-5f) * lng[ln] + lnb[ln];
    float g1 = gelu_exact(y);
    rowB[wv][ln] = g1;
    __syncthreads();
    float acc2 = br[ln];
    #pragma unroll 8
    for (int i = 0; i < 64; ++i) acc2 += rowB[wv][i] * wr[i * 64 + ln];
    float mu2 = wsum64(acc2) * (1.f / 64.f);
    float dv2 = acc2 - mu2;
    float var2 = wsum64(dv2 * dv2) * (1.f / 64.f);
    float y2 = dv2 * rsqrtf(var2 + 1e-5f) * lrg[ln] + lrb[ln];
    float g2 = gelu_exact(y2);
    out[(size_t)n * 64 + ln] = g1 + g2;
}

extern "C" void kernel_launch(void* const* d_in, const int* in_sizes, int n_in,
                              void* d_out, int out_size, void* d_ws, size_t ws_size,
                              hipStream_t stream) {
    const float* x    = (const float*)d_in[0];
    const int*   ei   = (const int*)d_in[1];
    const float* ea   = (const float*)d_in[2];
    const float* w1l  = (const float*)d_in[3];
    const float* w1r  = (const float*)d_in[4];
    const float* w1e  = (const float*)d_in[5];
    const float* att1 = (const float*)d_in[6];
    const float* b1   = (const float*)d_in[7];
    const float* w2l  = (const float*)d_in[8];
    const float* w2r  = (const float*)d_in[9];
    const float* w2e  = (const float*)d_in[10];
    const float* att2 = (const float*)d_in[11];
    const float* b2   = (const float*)d_in[12];
    const float* wc   = (const float*)d_in[13];
    const float* bc   = (const float*)d_in[14];
    const float* lng  = (const float*)d_in[15];
    const float* lnb  = (const float*)d_in[16];
    const float* wr   = (const float*)d_in[17];
    const float* br   = (const float*)d_in[18];
    const float* lrg  = (const float*)d_in[19];
    const float* lrb  = (const float*)d_in[20];

    float* ws = (float*)d_ws;
    const size_t N128 = (size_t)NNODE * 128;
    float* xl = ws;
    float* xr = xl + N128;
    float* h1 = xr + N128;
    float* h2 = h1 + N128;
    int*   deg     = (int*)(h2 + (size_t)NNODE * 64);
    int*   partial = deg + NNODE;
    int*   base    = partial + NNODE;         // NNODE+1
    int*   cursor  = base + NNODE + 1;
    int*   bsum    = cursor + NNODE;          // 256
    int*   boff    = bsum + 256;              // 256
    int*   srcS    = boff + 256;              // NEDGE
    float* eaS     = (float*)(srcS + NEDGE);  // NEDGE

    const int EB = NEDGE / 256;       // 3125
    const int NB8 = NNODE / 8;        // 6250
    const int NB4 = NNODE / 4;        // 12500

    // ---- CSR build (dst-sorted) ----
    fill_u32<<<NBLK_SCAN, 256, 0, stream>>>((unsigned*)deg, 0u, NNODE);
    build_deg<<<EB, 256, 0, stream>>>(ei, deg);
    scan1<<<NBLK_SCAN, 256, 0, stream>>>(deg, partial, bsum);
    scan2<<<1, 256, 0, stream>>>(bsum, boff);
    scan3<<<NBLK_SCAN, 256, 0, stream>>>(partial, boff, base, cursor);
    scatter_edges<<<EB, 256, 0, stream>>>(ei, ea, cursor, srcS, eaS);

    // ---- layer 1 ----
    node_xform1<<<NB8, 256, 0, stream>>>(x, w1l, w1r, xl, xr);
    fused1<<<NB4, 256, 0, stream>>>(base, srcS, eaS, xl, xr, w1e, att1, b1, h1);

    // ---- layer 2 ----
    node_xform2<<<NB8, 256, 0, stream>>>(h1, w2l, w2r, xl, xr);
    fused2<<<NB4, 256, 0, stream>>>(base, srcS, eaS, xl, xr, w2e, att2, b2, h2);

    // ---- classifier ----
    classifier<<<NB4, 256, 0, stream>>>(h2, wc, bc, lng, lnb, wr, br, lrg, lrb,
                                        (float*)d_out);
}

// Round 4
// 402.860 us; speedup vs baseline: 29.8169x; 1.2066x over previous
//
#include <hip/hip_runtime.h>
#include <math.h>

#define NNODE 50000
#define NEDGE 800000
#define NBLK_SCAN 196   // ceil(50000/256)

__device__ __forceinline__ float wsum64(float v) {
    #pragma unroll
    for (int m = 32; m >= 1; m >>= 1) v += __shfl_xor(v, m, 64);
    return v;
}

__device__ __forceinline__ float gelu_exact(float x) {
    return 0.5f * x * (1.0f + erff(x * 0.70710678118654752f));
}

__device__ __forceinline__ float lrelu(float z) { return z > 0.f ? z : 0.2f * z; }

// ---------------- utility ----------------
__global__ void fill_u32(unsigned* __restrict__ p, unsigned v, int n) {
    int i = blockIdx.x * blockDim.x + threadIdx.x;
    if (i < n) p[i] = v;
}

// ---------------- CSR build ----------------
__global__ __launch_bounds__(256) void build_deg(const int* __restrict__ ei, int* __restrict__ deg) {
    int e = blockIdx.x * 256 + threadIdx.x;
    if (e >= NEDGE) return;
    atomicAdd(&deg[ei[NEDGE + e]], 1);
}

__global__ __launch_bounds__(256) void scan1(const int* __restrict__ deg,
                                             int* __restrict__ partial,
                                             int* __restrict__ bsum) {
    __shared__ int tmp[256];
    int t = threadIdx.x;
    int gid = blockIdx.x * 256 + t;
    int v = (gid < NNODE) ? deg[gid] : 0;
    tmp[t] = v;
    __syncthreads();
    #pragma unroll
    for (int off = 1; off < 256; off <<= 1) {
        int u = (t >= off) ? tmp[t - off] : 0;
        __syncthreads();
        tmp[t] += u;
        __syncthreads();
    }
    if (gid < NNODE) partial[gid] = tmp[t] - v;   // exclusive
    if (t == 255) bsum[blockIdx.x] = tmp[255];
}

__global__ __launch_bounds__(256) void scan2(int* __restrict__ bsum, int* __restrict__ boff) {
    __shared__ int tmp[256];
    int t = threadIdx.x;
    int v = (t < NBLK_SCAN) ? bsum[t] : 0;
    tmp[t] = v;
    __syncthreads();
    #pragma unroll
    for (int off = 1; off < 256; off <<= 1) {
        int u = (t >= off) ? tmp[t - off] : 0;
        __syncthreads();
        tmp[t] += u;
        __syncthreads();
    }
    if (t < NBLK_SCAN) boff[t] = tmp[t] - v;      // exclusive
}

__global__ __launch_bounds__(256) void scan3(const int* __restrict__ partial,
                                             const int* __restrict__ boff,
                                             int* __restrict__ base,
                                             int* __restrict__ cursor) {
    int gid = blockIdx.x * 256 + threadIdx.x;
    if (gid < NNODE) {
        int b = partial[gid] + boff[blockIdx.x];
        base[gid] = b;
        cursor[gid] = b;
    }
    if (gid == 0) base[NNODE] = NEDGE;
}

__global__ __launch_bounds__(256) void scatter_edges(const int* __restrict__ ei,
                                                     const float* __restrict__ ea,
                                                     int* __restrict__ cursor,
                                                     int2* __restrict__ se) {
    int e = blockIdx.x * 256 + threadIdx.x;
    if (e >= NEDGE) return;
    int d = ei[NEDGE + e];
    int i = atomicAdd(&cursor[d], 1);
    se[i] = make_int2(ei[e], __float_as_int(ea[e]));
}

// ---------------- node transforms: 8 nodes/block for weight reuse ----------------
__global__ __launch_bounds__(256) void node_xform1(const float* __restrict__ x,
                                                   const float* __restrict__ wl,
                                                   const float* __restrict__ wr,
                                                   float* __restrict__ xl,
                                                   float* __restrict__ xr) {
    __shared__ float xrow[8][64];
    int t = threadIdx.x;
    int n0 = blockIdx.x * 8;
    for (int k = t; k < 8 * 64; k += 256) xrow[k >> 6][k & 63] = x[(size_t)n0 * 64 + k];
    __syncthreads();
    const float* w;
    float* o;
    int c;
    if (t < 128) { w = wl; c = t; o = xl; }
    else         { w = wr; c = t - 128; o = xr; }
    float acc[8] = {0.f, 0.f, 0.f, 0.f, 0.f, 0.f, 0.f, 0.f};
    for (int i = 0; i < 64; ++i) {
        float wv = w[i * 128 + c];
        #pragma unroll
        for (int k = 0; k < 8; ++k) acc[k] += xrow[k][i] * wv;
    }
    #pragma unroll
    for (int k = 0; k < 8; ++k) o[(size_t)(n0 + k) * 128 + c] = acc[k];
}

__global__ __launch_bounds__(256) void node_xform2(const float* __restrict__ h1,
                                                   const float* __restrict__ wl,
                                                   const float* __restrict__ wr,
                                                   float* __restrict__ xl,
                                                   float* __restrict__ xr) {
    __shared__ float hrow[8][128];
    int t = threadIdx.x;
    int n0 = blockIdx.x * 8;
    for (int k = t; k < 8 * 128; k += 256) hrow[k >> 7][k & 127] = h1[(size_t)n0 * 128 + k];
    __syncthreads();
    const float* w;
    float* o;
    int c;
    if (t < 128) { w = wl; c = t; o = xl; }
    else         { w = wr; c = t - 128; o = xr; }
    float acc[8] = {0.f, 0.f, 0.f, 0.f, 0.f, 0.f, 0.f, 0.f};
    for (int i = 0; i < 128; ++i) {
        float wv = w[i * 128 + c];
        #pragma unroll
        for (int k = 0; k < 8; ++k) acc[k] += hrow[k][i] * wv;
    }
    #pragma unroll
    for (int k = 0; k < 8; ++k) o[(size_t)(n0 + k) * 128 + c] = acc[k];
}

// ---------------- fused online-softmax GAT layer 1 (H=8, C=16) ----------------
// one wave per node; lane owns 2 channels; 8-lane groups = one head
// branchless online softmax + lookahead-1 software pipeline
__global__ __launch_bounds__(256) void fused1(const int* __restrict__ base,
                                              const int2* __restrict__ se,
                                              const float* __restrict__ xl,
                                              const float* __restrict__ xr,
                                              const float* __restrict__ w1e,
                                              const float* __restrict__ att1,
                                              const float* __restrict__ b1,
                                              float* __restrict__ h1) {
    int t = threadIdx.x;
    int wv = t >> 6, ln = t & 63;
    int n = blockIdx.x * 4 + wv;
    int ch = 2 * ln;
    float xr0 = xr[(size_t)n * 128 + ch], xr1 = xr[(size_t)n * 128 + ch + 1];
    float we0 = w1e[ch], we1 = w1e[ch + 1];
    float at0 = att1[ch], at1 = att1[ch + 1];
    int i0 = base[n], i1 = base[n + 1];
    float m = -INFINITY, den = 0.f, o0 = 0.f, o1 = 0.f;
    if (i0 < i1) {
        int2 r = se[i0];
        float x0 = xl[(size_t)r.x * 128 + ch];
        float x1 = xl[(size_t)r.x * 128 + ch + 1];
        float a = __int_as_float(r.y);
        for (int i = i0 + 1; i < i1; ++i) {
            // issue next edge's loads before current compute
            int2 rn = se[i];
            float nx0 = xl[(size_t)rn.x * 128 + ch];
            float nx1 = xl[(size_t)rn.x * 128 + ch + 1];
            float na = __int_as_float(rn.y);
            float part = lrelu(x0 + xr0 + a * we0) * at0 + lrelu(x1 + xr1 + a * we1) * at1;
            part += __shfl_xor(part, 1, 64);
            part += __shfl_xor(part, 2, 64);
            part += __shfl_xor(part, 4, 64);
            float mn = fmaxf(m, part);
            float sc = __expf(m - mn);
            float p  = __expf(part - mn);
            den = den * sc + p;
            o0  = o0 * sc + p * x0;
            o1  = o1 * sc + p * x1;
            m = mn;
            x0 = nx0; x1 = nx1; a = na;
        }
        float part = lrelu(x0 + xr0 + a * we0) * at0 + lrelu(x1 + xr1 + a * we1) * at1;
        part += __shfl_xor(part, 1, 64);
        part += __shfl_xor(part, 2, 64);
        part += __shfl_xor(part, 4, 64);
        float mn = fmaxf(m, part);
        float sc = __expf(m - mn);
        float p  = __expf(part - mn);
        den = den * sc + p;
        o0  = o0 * sc + p * x0;
        o1  = o1 * sc + p * x1;
    }
    float inv = 1.f / (den + 1e-16f);
    float v0 = o0 * inv + b1[ch];
    float v1 = o1 * inv + b1[ch + 1];
    h1[(size_t)n * 128 + ch]     = v0 > 0.f ? v0 : 0.f;
    h1[(size_t)n * 128 + ch + 1] = v1 > 0.f ? v1 : 0.f;
}

// ---------------- fused online-softmax GAT layer 2 (H=2, C=64, mean) ----------------
__global__ __launch_bounds__(256) void fused2(const int* __restrict__ base,
                                              const int2* __restrict__ se,
                                              const float* __restrict__ xl,
                                              const float* __restrict__ xr,
                                              const float* __restrict__ w2e,
                                              const float* __restrict__ att2,
                                              const float* __restrict__ b2,
                                              float* __restrict__ h2) {
    int t = threadIdx.x;
    int wv = t >> 6, ln = t & 63;
    int n = blockIdx.x * 4 + wv;
    int ch = 2 * ln;
    float xr0 = xr[(size_t)n * 128 + ch], xr1 = xr[(size_t)n * 128 + ch + 1];
    float we0 = w2e[ch], we1 = w2e[ch + 1];
    float at0 = att2[ch], at1 = att2[ch + 1];
    int i0 = base[n], i1 = base[n + 1];
    float m = -INFINITY, den = 0.f, o0 = 0.f, o1 = 0.f;
    if (i0 < i1) {
        int2 r = se[i0];
        float x0 = xl[(size_t)r.x * 128 + ch];
        float x1 = xl[(size_t)r.x * 128 + ch + 1];
        float a = __int_as_float(r.y);
        for (int i = i0 + 1; i < i1; ++i) {
            int2 rn = se[i];
            float nx0 = xl[(size_t)rn.x * 128 + ch];
            float nx1 = xl[(size_t)rn.x * 128 + ch + 1];
            float na = __int_as_float(rn.y);
            float part = lrelu(x0 + xr0 + a * we0) * at0 + lrelu(x1 + xr1 + a * we1) * at1;
            part += __shfl_xor(part, 1, 64);
            part += __shfl_xor(part, 2, 64);
            part += __shfl_xor(part, 4, 64);
            part += __shfl_xor(part, 8, 64);
            part += __shfl_xor(part, 16, 64);
            float mn = fmaxf(m, part);
            float sc = __expf(m - mn);
            float p  = __expf(part - mn);
            den = den * sc + p;
            o0  = o0 * sc + p * x0;
            o1  = o1 * sc + p * x1;
            m = mn;
            x0 = nx0; x1 = nx1; a = na;
        }
        float part = lrelu(x0 + xr0 + a * we0) * at0 + lrelu(x1 + xr1 + a * we1) * at1;
        part += __shfl_xor(part, 1, 64);
        part += __shfl_xor(part, 2, 64);
        part += __shfl_xor(part, 4, 64);
        part += __shfl_xor(part, 8, 64);
        part += __shfl_xor(part, 16, 64);
        float mn = fmaxf(m, part);
        float sc = __expf(m - mn);
        float p  = __expf(part - mn);
        den = den * sc + p;
        o0  = o0 * sc + p * x0;
        o1  = o1 * sc + p * x1;
    }
    float inv = 1.f / (den + 1e-16f);
    float v0 = o0 * inv, v1 = o1 * inv;
    float u0 = __shfl_xor(v0, 32, 64);
    float u1 = __shfl_xor(v1, 32, 64);
    if (ln < 32) {
        int c = 2 * ln;
        float r0 = 0.5f * (v0 + u0) + b2[c];
        float r1 = 0.5f * (v1 + u1) + b2[c + 1];
        h2[(size_t)n * 64 + c]     = r0 > 0.f ? r0 : 0.f;
        h2[(size_t)n * 64 + c + 1] = r1 > 0.f ? r1 : 0.f;
    }
}

// ---------------- classifier: one wave (64 lanes) per node ----------------
__global__ __launch_bounds__(256) void classifier(const float* __restrict__ h2,
                                                  const float* __restrict__ wc,
                                                  const float* __restrict__ bc,
                                                  const float* __restrict__ lng,
                                                  const float* __restrict__ lnb,
                                                  const float* __restrict__ wr,
                                                  const float* __restrict__ br,
                                                  const float* __restrict__ lrg,
                                                  const float* __restrict__ lrb,
                                                  float* __restrict__ out) {
    __shared__ float rowA[4][64];
    __shared__ float rowB[4][64];
    int t = threadIdx.x;
    int wv = t >> 6, ln = t & 63;
    int n = blockIdx.x * 4 + wv;
    rowA[wv][ln] = h2[(size_t)n * 64 + ln];
    __syncthreads();
    float acc = bc[ln];
    #pragma unroll 8
    for (int i = 0; i < 64; ++i) acc += rowA[wv][i] * wc[i * 64 + ln];
    float mu = wsum64(acc) * (1.f / 64.f);
    float dv = acc - mu;
    float var = wsum64(dv * dv) * (1.f / 64.f);
    float y = dv * rsqrtf(var + 1e-5f) * lng[ln] + lnb[ln];
    float g1 = gelu_exact(y);
    rowB[wv][ln] = g1;
    __syncthreads();
    float acc2 = br[ln];
    #pragma unroll 8
    for (int i = 0; i < 64; ++i) acc2 += rowB[wv][i] * wr[i * 64 + ln];
    float mu2 = wsum64(acc2) * (1.f / 64.f);
    float dv2 = acc2 - mu2;
    float var2 = wsum64(dv2 * dv2) * (1.f / 64.f);
    float y2 = dv2 * rsqrtf(var2 + 1e-5f) * lrg[ln] + lrb[ln];
    float g2 = gelu_exact(y2);
    out[(size_t)n * 64 + ln] = g1 + g2;
}

extern "C" void kernel_launch(void* const* d_in, const int* in_sizes, int n_in,
                              void* d_out, int out_size, void* d_ws, size_t ws_size,
                              hipStream_t stream) {
    const float* x    = (const float*)d_in[0];
    const int*   ei   = (const int*)d_in[1];
    const float* ea   = (const float*)d_in[2];
    const float* w1l  = (const float*)d_in[3];
    const float* w1r  = (const float*)d_in[4];
    const float* w1e  = (const float*)d_in[5];
    const float* att1 = (const float*)d_in[6];
    const float* b1   = (const float*)d_in[7];
    const float* w2l  = (const float*)d_in[8];
    const float* w2r  = (const float*)d_in[9];
    const float* w2e  = (const float*)d_in[10];
    const float* att2 = (const float*)d_in[11];
    const float* b2   = (const float*)d_in[12];
    const float* wc   = (const float*)d_in[13];
    const float* bc   = (const float*)d_in[14];
    const float* lng  = (const float*)d_in[15];
    const float* lnb  = (const float*)d_in[16];
    const float* wr   = (const float*)d_in[17];
    const float* br   = (const float*)d_in[18];
    const float* lrg  = (const float*)d_in[19];
    const float* lrb  = (const float*)d_in[20];

    float* ws = (float*)d_ws;
    const size_t N128 = (size_t)NNODE * 128;
    float* xl = ws;
    float* xr = xl + N128;
    float* h1 = xr + N128;
    float* h2 = h1 + N128;
    int2*  se      = (int2*)(h2 + (size_t)NNODE * 64);   // NEDGE (8B aligned: even float offset)
    int*   deg     = (int*)(se + NEDGE);
    int*   partial = deg + NNODE;
    int*   base    = partial + NNODE;         // NNODE+1
    int*   cursor  = base + NNODE + 1;
    int*   bsum    = cursor + NNODE;          // 256
    int*   boff    = bsum + 256;              // 256

    const int EB = NEDGE / 256;       // 3125
    const int NB8 = NNODE / 8;        // 6250
    const int NB4 = NNODE / 4;        // 12500

    // ---- CSR build (dst-sorted) ----
    fill_u32<<<NBLK_SCAN, 256, 0, stream>>>((unsigned*)deg, 0u, NNODE);
    build_deg<<<EB, 256, 0, stream>>>(ei, deg);
    scan1<<<NBLK_SCAN, 256, 0, stream>>>(deg, partial, bsum);
    scan2<<<1, 256, 0, stream>>>(bsum, boff);
    scan3<<<NBLK_SCAN, 256, 0, stream>>>(partial, boff, base, cursor);
    scatter_edges<<<EB, 256, 0, stream>>>(ei, ea, cursor, se);

    // ---- layer 1 ----
    node_xform1<<<NB8, 256, 0, stream>>>(x, w1l, w1r, xl, xr);
    fused1<<<NB4, 256, 0, stream>>>(base, se, xl, xr, w1e, att1, b1, h1);

    // ---- layer 2 ----
    node_xform2<<<NB8, 256, 0, stream>>>(h1, w2l, w2r, xl, xr);
    fused2<<<NB4, 256, 0, stream>>>(base, se, xl, xr, w2e, att2, b2, h2);

    // ---- classifier ----
    classifier<<<NB4, 256, 0, stream>>>(h2, wc, bc, lng, lnb, wr, br, lrg, lrb,
                                        (float*)d_out);
}

// Round 5
// 373.316 us; speedup vs baseline: 32.1765x; 1.0791x over previous
//
#include <hip/hip_runtime.h>
#include <math.h>

#define NNODE 50000
#define NEDGE 800000
#define NBLK_SCAN 196   // ceil(50000/256)

__device__ __forceinline__ float wsum64(float v) {
    #pragma unroll
    for (int m = 32; m >= 1; m >>= 1) v += __shfl_xor(v, m, 64);
    return v;
}

__device__ __forceinline__ float gelu_exact(float x) {
    return 0.5f * x * (1.0f + erff(x * 0.70710678118654752f));
}

__device__ __forceinline__ float lrelu(float z) { return z > 0.f ? z : 0.2f * z; }

// ---------------- utility ----------------
__global__ void fill_u32(unsigned* __restrict__ p, unsigned v, int n) {
    int i = blockIdx.x * blockDim.x + threadIdx.x;
    if (i < n) p[i] = v;
}

// ---------------- CSR build ----------------
__global__ __launch_bounds__(256) void build_deg(const int* __restrict__ ei, int* __restrict__ deg) {
    int e = blockIdx.x * 256 + threadIdx.x;
    if (e >= NEDGE) return;
    atomicAdd(&deg[ei[NEDGE + e]], 1);
}

__global__ __launch_bounds__(256) void scan1(const int* __restrict__ deg,
                                             int* __restrict__ partial,
                                             int* __restrict__ bsum) {
    __shared__ int tmp[256];
    int t = threadIdx.x;
    int gid = blockIdx.x * 256 + t;
    int v = (gid < NNODE) ? deg[gid] : 0;
    tmp[t] = v;
    __syncthreads();
    #pragma unroll
    for (int off = 1; off < 256; off <<= 1) {
        int u = (t >= off) ? tmp[t - off] : 0;
        __syncthreads();
        tmp[t] += u;
        __syncthreads();
    }
    if (gid < NNODE) partial[gid] = tmp[t] - v;   // exclusive
    if (t == 255) bsum[blockIdx.x] = tmp[255];
}

__global__ __launch_bounds__(256) void scan2(int* __restrict__ bsum, int* __restrict__ boff) {
    __shared__ int tmp[256];
    int t = threadIdx.x;
    int v = (t < NBLK_SCAN) ? bsum[t] : 0;
    tmp[t] = v;
    __syncthreads();
    #pragma unroll
    for (int off = 1; off < 256; off <<= 1) {
        int u = (t >= off) ? tmp[t - off] : 0;
        __syncthreads();
        tmp[t] += u;
        __syncthreads();
    }
    if (t < NBLK_SCAN) boff[t] = tmp[t] - v;      // exclusive
}

__global__ __launch_bounds__(256) void scan3(const int* __restrict__ partial,
                                             const int* __restrict__ boff,
                                             int* __restrict__ base,
                                             int* __restrict__ cursor) {
    int gid = blockIdx.x * 256 + threadIdx.x;
    if (gid < NNODE) {
        int b = partial[gid] + boff[blockIdx.x];
        base[gid] = b;
        cursor[gid] = b;
    }
    if (gid == 0) base[NNODE] = NEDGE;
}

__global__ __launch_bounds__(256) void scatter_edges(const int* __restrict__ ei,
                                                     const float* __restrict__ ea,
                                                     int* __restrict__ cursor,
                                                     int2* __restrict__ se) {
    int e = blockIdx.x * 256 + threadIdx.x;
    if (e >= NEDGE) return;
    int d = ei[NEDGE + e];
    int i = atomicAdd(&cursor[d], 1);
    se[i] = make_int2(ei[e], __float_as_int(ea[e]));
}

// ---------------- node transforms: 8 nodes/block for weight reuse ----------------
__global__ __launch_bounds__(256) void node_xform1(const float* __restrict__ x,
                                                   const float* __restrict__ wl,
                                                   const float* __restrict__ wr,
                                                   float* __restrict__ xl,
                                                   float* __restrict__ xr) {
    __shared__ float xrow[8][64];
    int t = threadIdx.x;
    int n0 = blockIdx.x * 8;
    for (int k = t; k < 8 * 64; k += 256) xrow[k >> 6][k & 63] = x[(size_t)n0 * 64 + k];
    __syncthreads();
    const float* w;
    float* o;
    int c;
    if (t < 128) { w = wl; c = t; o = xl; }
    else         { w = wr; c = t - 128; o = xr; }
    float acc[8] = {0.f, 0.f, 0.f, 0.f, 0.f, 0.f, 0.f, 0.f};
    for (int i = 0; i < 64; ++i) {
        float wv = w[i * 128 + c];
        #pragma unroll
        for (int k = 0; k < 8; ++k) acc[k] += xrow[k][i] * wv;
    }
    #pragma unroll
    for (int k = 0; k < 8; ++k) o[(size_t)(n0 + k) * 128 + c] = acc[k];
}

__global__ __launch_bounds__(256) void node_xform2(const float* __restrict__ h1,
                                                   const float* __restrict__ wl,
                                                   const float* __restrict__ wr,
                                                   float* __restrict__ xl,
                                                   float* __restrict__ xr) {
    __shared__ float hrow[8][128];
    int t = threadIdx.x;
    int n0 = blockIdx.x * 8;
    for (int k = t; k < 8 * 128; k += 256) hrow[k >> 7][k & 127] = h1[(size_t)n0 * 128 + k];
    __syncthreads();
    const float* w;
    float* o;
    int c;
    if (t < 128) { w = wl; c = t; o = xl; }
    else         { w = wr; c = t - 128; o = xr; }
    float acc[8] = {0.f, 0.f, 0.f, 0.f, 0.f, 0.f, 0.f, 0.f};
    for (int i = 0; i < 128; ++i) {
        float wv = w[i * 128 + c];
        #pragma unroll
        for (int k = 0; k < 8; ++k) acc[k] += hrow[k][i] * wv;
    }
    #pragma unroll
    for (int k = 0; k < 8; ++k) o[(size_t)(n0 + k) * 128 + c] = acc[k];
}

// ---------------- fused online-softmax GAT layer 1 (H=8, C=16) ----------------
// one wave per node; each HALF-wave (32 lanes) processes alternating edges.
// lane owns 4 channels (dwordx4); 4-lane groups = one head -> 2 shuffles.
__global__ __launch_bounds__(256) void fused1(const int* __restrict__ base,
                                              const int2* __restrict__ se,
                                              const float* __restrict__ xl,
                                              const float* __restrict__ xr,
                                              const float* __restrict__ w1e,
                                              const float* __restrict__ att1,
                                              const float* __restrict__ b1,
                                              float* __restrict__ h1) {
    int t = threadIdx.x;
    int wv = t >> 6, ln = t & 63;
    int half = ln >> 5, sub = ln & 31;
    int n = blockIdx.x * 4 + wv;
    int ch = sub * 4;
    float4 xrv = *(const float4*)(xr + (size_t)n * 128 + ch);
    float4 wev = *(const float4*)(w1e + ch);
    float4 atv = *(const float4*)(att1 + ch);
    int i0 = base[n], i1 = base[n + 1];
    float m = -1e30f, den = 0.f;
    float4 o = make_float4(0.f, 0.f, 0.f, 0.f);
    int i = i0 + half;
    if (i < i1) {
        int2 r = se[i];
        float4 xv = *(const float4*)(xl + (size_t)r.x * 128 + ch);
        float a = __int_as_float(r.y);
        for (i += 2; i < i1; i += 2) {
            int2 rn = se[i];
            float4 nxv = *(const float4*)(xl + (size_t)rn.x * 128 + ch);
            float na = __int_as_float(rn.y);
            float part = lrelu(fmaf(a, wev.x, xv.x + xrv.x)) * atv.x
                       + lrelu(fmaf(a, wev.y, xv.y + xrv.y)) * atv.y
                       + lrelu(fmaf(a, wev.z, xv.z + xrv.z)) * atv.z
                       + lrelu(fmaf(a, wev.w, xv.w + xrv.w)) * atv.w;
            part += __shfl_xor(part, 1, 64);
            part += __shfl_xor(part, 2, 64);
            float mn = fmaxf(m, part);
            float sc = __expf(m - mn);
            float p  = __expf(part - mn);
            den = den * sc + p;
            o.x = o.x * sc + p * xv.x;
            o.y = o.y * sc + p * xv.y;
            o.z = o.z * sc + p * xv.z;
            o.w = o.w * sc + p * xv.w;
            m = mn;
            xv = nxv; a = na;
        }
        float part = lrelu(fmaf(a, wev.x, xv.x + xrv.x)) * atv.x
                   + lrelu(fmaf(a, wev.y, xv.y + xrv.y)) * atv.y
                   + lrelu(fmaf(a, wev.z, xv.z + xrv.z)) * atv.z
                   + lrelu(fmaf(a, wev.w, xv.w + xrv.w)) * atv.w;
        part += __shfl_xor(part, 1, 64);
        part += __shfl_xor(part, 2, 64);
        float mn = fmaxf(m, part);
        float sc = __expf(m - mn);
        float p  = __expf(part - mn);
        den = den * sc + p;
        o.x = o.x * sc + p * xv.x;
        o.y = o.y * sc + p * xv.y;
        o.z = o.z * sc + p * xv.z;
        o.w = o.w * sc + p * xv.w;
        m = mn;
    }
    // merge the two half-wave softmax states
    float m2   = __shfl_xor(m, 32, 64);
    float den2 = __shfl_xor(den, 32, 64);
    float4 o2;
    o2.x = __shfl_xor(o.x, 32, 64);
    o2.y = __shfl_xor(o.y, 32, 64);
    o2.z = __shfl_xor(o.z, 32, 64);
    o2.w = __shfl_xor(o.w, 32, 64);
    float mn = fmaxf(m, m2);
    float s1 = __expf(m - mn), s2 = __expf(m2 - mn);
    den = den * s1 + den2 * s2;
    float inv = 1.f / (den + 1e-16f);
    if (half == 0) {
        float4 bv = *(const float4*)(b1 + ch);
        float4 res;
        res.x = fmaxf((o.x * s1 + o2.x * s2) * inv + bv.x, 0.f);
        res.y = fmaxf((o.y * s1 + o2.y * s2) * inv + bv.y, 0.f);
        res.z = fmaxf((o.z * s1 + o2.z * s2) * inv + bv.z, 0.f);
        res.w = fmaxf((o.w * s1 + o2.w * s2) * inv + bv.w, 0.f);
        *(float4*)(h1 + (size_t)n * 128 + ch) = res;
    }
}

// ---------------- fused online-softmax GAT layer 2 (H=2, C=64, mean) ----------------
// same half-wave scheme; 16-lane groups = one head -> 4 shuffles.
__global__ __launch_bounds__(256) void fused2(const int* __restrict__ base,
                                              const int2* __restrict__ se,
                                              const float* __restrict__ xl,
                                              const float* __restrict__ xr,
                                              const float* __restrict__ w2e,
                                              const float* __restrict__ att2,
                                              const float* __restrict__ b2,
                                              float* __restrict__ h2) {
    int t = threadIdx.x;
    int wv = t >> 6, ln = t & 63;
    int half = ln >> 5, sub = ln & 31;
    int n = blockIdx.x * 4 + wv;
    int ch = sub * 4;
    float4 xrv = *(const float4*)(xr + (size_t)n * 128 + ch);
    float4 wev = *(const float4*)(w2e + ch);
    float4 atv = *(const float4*)(att2 + ch);
    int i0 = base[n], i1 = base[n + 1];
    float m = -1e30f, den = 0.f;
    float4 o = make_float4(0.f, 0.f, 0.f, 0.f);
    int i = i0 + half;
    if (i < i1) {
        int2 r = se[i];
        float4 xv = *(const float4*)(xl + (size_t)r.x * 128 + ch);
        float a = __int_as_float(r.y);
        for (i += 2; i < i1; i += 2) {
            int2 rn = se[i];
            float4 nxv = *(const float4*)(xl + (size_t)rn.x * 128 + ch);
            float na = __int_as_float(rn.y);
            float part = lrelu(fmaf(a, wev.x, xv.x + xrv.x)) * atv.x
                       + lrelu(fmaf(a, wev.y, xv.y + xrv.y)) * atv.y
                       + lrelu(fmaf(a, wev.z, xv.z + xrv.z)) * atv.z
                       + lrelu(fmaf(a, wev.w, xv.w + xrv.w)) * atv.w;
            part += __shfl_xor(part, 1, 64);
            part += __shfl_xor(part, 2, 64);
            part += __shfl_xor(part, 4, 64);
            part += __shfl_xor(part, 8, 64);
            float mn = fmaxf(m, part);
            float sc = __expf(m - mn);
            float p  = __expf(part - mn);
            den = den * sc + p;
            o.x = o.x * sc + p * xv.x;
            o.y = o.y * sc + p * xv.y;
            o.z = o.z * sc + p * xv.z;
            o.w = o.w * sc + p * xv.w;
            m = mn;
            xv = nxv; a = na;
        }
        float part = lrelu(fmaf(a, wev.x, xv.x + xrv.x)) * atv.x
                   + lrelu(fmaf(a, wev.y, xv.y + xrv.y)) * atv.y
                   + lrelu(fmaf(a, wev.z, xv.z + xrv.z)) * atv.z
                   + lrelu(fmaf(a, wev.w, xv.w + xrv.w)) * atv.w;
        part += __shfl_xor(part, 1, 64);
        part += __shfl_xor(part, 2, 64);
        part += __shfl_xor(part, 4, 64);
        part += __shfl_xor(part, 8, 64);
        float mn = fmaxf(m, part);
        float sc = __expf(m - mn);
        float p  = __expf(part - mn);
        den = den * sc + p;
        o.x = o.x * sc + p * xv.x;
        o.y = o.y * sc + p * xv.y;
        o.z = o.z * sc + p * xv.z;
        o.w = o.w * sc + p * xv.w;
        m = mn;
    }
    // merge the two half-wave softmax states
    float m2   = __shfl_xor(m, 32, 64);
    float den2 = __shfl_xor(den, 32, 64);
    float4 o2;
    o2.x = __shfl_xor(o.x, 32, 64);
    o2.y = __shfl_xor(o.y, 32, 64);
    o2.z = __shfl_xor(o.z, 32, 64);
    o2.w = __shfl_xor(o.w, 32, 64);
    float mn = fmaxf(m, m2);
    float s1 = __expf(m - mn), s2 = __expf(m2 - mn);
    den = den * s1 + den2 * s2;
    float inv = 1.f / (den + 1e-16f);
    float4 v;
    v.x = (o.x * s1 + o2.x * s2) * inv;
    v.y = (o.y * s1 + o2.y * s2) * inv;
    v.z = (o.z * s1 + o2.z * s2) * inv;
    v.w = (o.w * s1 + o2.w * s2) * inv;
    // mean over the two heads: partner lane is sub ^ 16 (head0 ch c <-> head1 ch c+64)
    float4 u;
    u.x = __shfl_xor(v.x, 16, 64);
    u.y = __shfl_xor(v.y, 16, 64);
    u.z = __shfl_xor(v.z, 16, 64);
    u.w = __shfl_xor(v.w, 16, 64);
    if (half == 0 && sub < 16) {
        float4 bv = *(const float4*)(b2 + ch);
        float4 res;
        res.x = fmaxf(0.5f * (v.x + u.x) + bv.x, 0.f);
        res.y = fmaxf(0.5f * (v.y + u.y) + bv.y, 0.f);
        res.z = fmaxf(0.5f * (v.z + u.z) + bv.z, 0.f);
        res.w = fmaxf(0.5f * (v.w + u.w) + bv.w, 0.f);
        *(float4*)(h2 + (size_t)n * 64 + ch) = res;
    }
}

// ---------------- classifier: one wave (64 lanes) per node ----------------
__global__ __launch_bounds__(256) void classifier(const float* __restrict__ h2,
                                                  const float* __restrict__ wc,
                                                  const float* __restrict__ bc,
                                                  const float* __restrict__ lng,
                                                  const float* __restrict__ lnb,
                                                  const float* __restrict__ wr,
                                                  const float* __restrict__ br,
                                                  const float* __restrict__ lrg,
                                                  const float* __restrict__ lrb,
                                                  float* __restrict__ out) {
    __shared__ float rowA[4][64];
    __shared__ float rowB[4][64];
    int t = threadIdx.x;
    int wv = t >> 6, ln = t & 63;
    int n = blockIdx.x * 4 + wv;
    rowA[wv][ln] = h2[(size_t)n * 64 + ln];
    __syncthreads();
    float acc = bc[ln];
    #pragma unroll 8
    for (int i = 0; i < 64; ++i) acc += rowA[wv][i] * wc[i * 64 + ln];
    float mu = wsum64(acc) * (1.f / 64.f);
    float dv = acc - mu;
    float var = wsum64(dv * dv) * (1.f / 64.f);
    float y = dv * rsqrtf(var + 1e-5f) * lng[ln] + lnb[ln];
    float g1 = gelu_exact(y);
    rowB[wv][ln] = g1;
    __syncthreads();
    float acc2 = br[ln];
    #pragma unroll 8
    for (int i = 0; i < 64; ++i) acc2 += rowB[wv][i] * wr[i * 64 + ln];
    float mu2 = wsum64(acc2) * (1.f / 64.f);
    float dv2 = acc2 - mu2;
    float var2 = wsum64(dv2 * dv2) * (1.f / 64.f);
    float y2 = dv2 * rsqrtf(var2 + 1e-5f) * lrg[ln] + lrb[ln];
    float g2 = gelu_exact(y2);
    out[(size_t)n * 64 + ln] = g1 + g2;
}

extern "C" void kernel_launch(void* const* d_in, const int* in_sizes, int n_in,
                              void* d_out, int out_size, void* d_ws, size_t ws_size,
                              hipStream_t stream) {
    const float* x    = (const float*)d_in[0];
    const int*   ei   = (const int*)d_in[1];
    const float* ea   = (const float*)d_in[2];
    const float* w1l  = (const float*)d_in[3];
    const float* w1r  = (const float*)d_in[4];
    const float* w1e  = (const float*)d_in[5];
    const float* att1 = (const float*)d_in[6];
    const float* b1   = (const float*)d_in[7];
    const float* w2l  = (const float*)d_in[8];
    const float* w2r  = (const float*)d_in[9];
    const float* w2e  = (const float*)d_in[10];
    const float* att2 = (const float*)d_in[11];
    const float* b2   = (const float*)d_in[12];
    const float* wc   = (const float*)d_in[13];
    const float* bc   = (const float*)d_in[14];
    const float* lng  = (const float*)d_in[15];
    const float* lnb  = (const float*)d_in[16];
    const float* wr   = (const float*)d_in[17];
    const float* br   = (const float*)d_in[18];
    const float* lrg  = (const float*)d_in[19];
    const float* lrb  = (const float*)d_in[20];

    float* ws = (float*)d_ws;
    const size_t N128 = (size_t)NNODE * 128;
    float* xl = ws;
    float* xr = xl + N128;
    float* h1 = xr + N128;
    float* h2 = h1 + N128;
    int2*  se      = (int2*)(h2 + (size_t)NNODE * 64);   // NEDGE (8B aligned)
    int*   deg     = (int*)(se + NEDGE);
    int*   partial = deg + NNODE;
    int*   base    = partial + NNODE;         // NNODE+1
    int*   cursor  = base + NNODE + 1;
    int*   bsum    = cursor + NNODE;          // 256
    int*   boff    = bsum + 256;              // 256

    const int EB = NEDGE / 256;       // 3125
    const int NB8 = NNODE / 8;        // 6250
    const int NB4 = NNODE / 4;        // 12500

    // ---- CSR build (dst-sorted) ----
    fill_u32<<<NBLK_SCAN, 256, 0, stream>>>((unsigned*)deg, 0u, NNODE);
    build_deg<<<EB, 256, 0, stream>>>(ei, deg);
    scan1<<<NBLK_SCAN, 256, 0, stream>>>(deg, partial, bsum);
    scan2<<<1, 256, 0, stream>>>(bsum, boff);
    scan3<<<NBLK_SCAN, 256, 0, stream>>>(partial, boff, base, cursor);
    scatter_edges<<<EB, 256, 0, stream>>>(ei, ea, cursor, se);

    // ---- layer 1 ----
    node_xform1<<<NB8, 256, 0, stream>>>(x, w1l, w1r, xl, xr);
    fused1<<<NB4, 256, 0, stream>>>(base, se, xl, xr, w1e, att1, b1, h1);

    // ---- layer 2 ----
    node_xform2<<<NB8, 256, 0, stream>>>(h1, w2l, w2r, xl, xr);
    fused2<<<NB4, 256, 0, stream>>>(base, se, xl, xr, w2e, att2, b2, h2);

    // ---- classifier ----
    classifier<<<NB4, 256, 0, stream>>>(h2, wc, bc, lng, lnb, wr, br, lrg, lrb,
                                        (float*)d_out);
}

// Round 6
// 351.611 us; speedup vs baseline: 34.1628x; 1.0617x over previous
//
#include <hip/hip_runtime.h>
#include <math.h>

#define NNODE 50000
#define NEDGE 800000
#define NBLK_SCAN 196   // ceil(50000/256)

__device__ __forceinline__ float wsum64(float v) {
    #pragma unroll
    for (int m = 32; m >= 1; m >>= 1) v += __shfl_xor(v, m, 64);
    return v;
}

__device__ __forceinline__ float gelu_exact(float x) {
    return 0.5f * x * (1.0f + erff(x * 0.70710678118654752f));
}

__device__ __forceinline__ float lrelu(float z) { return z > 0.f ? z : 0.2f * z; }

// ---------------- utility ----------------
__global__ void fill_u32(unsigned* __restrict__ p, unsigned v, int n) {
    int i = blockIdx.x * blockDim.x + threadIdx.x;
    if (i < n) p[i] = v;
}

// ---------------- CSR build ----------------
__global__ __launch_bounds__(256) void build_deg(const int* __restrict__ ei, int* __restrict__ deg) {
    int e = blockIdx.x * 256 + threadIdx.x;
    if (e >= NEDGE) return;
    atomicAdd(&deg[ei[NEDGE + e]], 1);
}

__global__ __launch_bounds__(256) void scan1(const int* __restrict__ deg,
                                             int* __restrict__ partial,
                                             int* __restrict__ bsum) {
    __shared__ int tmp[256];
    int t = threadIdx.x;
    int gid = blockIdx.x * 256 + t;
    int v = (gid < NNODE) ? deg[gid] : 0;
    tmp[t] = v;
    __syncthreads();
    #pragma unroll
    for (int off = 1; off < 256; off <<= 1) {
        int u = (t >= off) ? tmp[t - off] : 0;
        __syncthreads();
        tmp[t] += u;
        __syncthreads();
    }
    if (gid < NNODE) partial[gid] = tmp[t] - v;   // exclusive
    if (t == 255) bsum[blockIdx.x] = tmp[255];
}

__global__ __launch_bounds__(256) void scan2(int* __restrict__ bsum, int* __restrict__ boff) {
    __shared__ int tmp[256];
    int t = threadIdx.x;
    int v = (t < NBLK_SCAN) ? bsum[t] : 0;
    tmp[t] = v;
    __syncthreads();
    #pragma unroll
    for (int off = 1; off < 256; off <<= 1) {
        int u = (t >= off) ? tmp[t - off] : 0;
        __syncthreads();
        tmp[t] += u;
        __syncthreads();
    }
    if (t < NBLK_SCAN) boff[t] = tmp[t] - v;      // exclusive
}

__global__ __launch_bounds__(256) void scan3(const int* __restrict__ partial,
                                             const int* __restrict__ boff,
                                             int* __restrict__ base,
                                             int* __restrict__ cursor) {
    int gid = blockIdx.x * 256 + threadIdx.x;
    if (gid < NNODE) {
        int b = partial[gid] + boff[blockIdx.x];
        base[gid] = b;
        cursor[gid] = b;
    }
    if (gid == 0) base[NNODE] = NEDGE;
}

__global__ __launch_bounds__(256) void scatter_edges(const int* __restrict__ ei,
                                                     const float* __restrict__ ea,
                                                     int* __restrict__ cursor,
                                                     int2* __restrict__ se) {
    int e = blockIdx.x * 256 + threadIdx.x;
    if (e >= NEDGE) return;
    int d = ei[NEDGE + e];
    int i = atomicAdd(&cursor[d], 1);
    se[i] = make_int2(ei[e], __float_as_int(ea[e]));
}

// ---------------- node transform: 32 nodes/block, thread owns 4 cols x 8 nodes ----------
// in[N,K] @ wl[K,128] -> xl[N,128];  in[N,K] @ wr[K,128] -> xr[N,128]
// 256 threads: colgroup cg = t & 63 (cg<32 -> xl cols cg*4; cg>=32 -> xr cols (cg-32)*4)
//              nodesub  ns = t >> 6 (nodes ns*8 .. ns*8+7)
template<int K>
__global__ __launch_bounds__(256) void node_xform(const float* __restrict__ in,
                                                  const float* __restrict__ wl,
                                                  const float* __restrict__ wr,
                                                  float* __restrict__ xl,
                                                  float* __restrict__ xr) {
    __shared__ float xrow[32][K];
    int t = threadIdx.x;
    int n0 = blockIdx.x * 32;
    // stage 32 node rows (vectorized, guarded)
    for (int idx = t; idx < 32 * (K / 4); idx += 256) {
        int row = idx / (K / 4), c4 = idx % (K / 4);
        float4 v = make_float4(0.f, 0.f, 0.f, 0.f);
        if (n0 + row < NNODE) v = ((const float4*)(in + (size_t)(n0 + row) * K))[c4];
        ((float4*)xrow[row])[c4] = v;
    }
    __syncthreads();
    int cg = t & 63, ns = t >> 6;
    const float* wsel = (cg < 32) ? wl : wr;
    float* osel = (cg < 32) ? xl : xr;
    int ccol = (cg & 31) * 4;
    const float* wp = wsel + ccol;
    const float* xbase = xrow[ns * 8];
    float4 acc[8];
    #pragma unroll
    for (int k = 0; k < 8; ++k) acc[k] = make_float4(0.f, 0.f, 0.f, 0.f);
    for (int i = 0; i < K; i += 4) {
        float4 w0 = *(const float4*)(wp + (size_t)(i + 0) * 128);
        float4 w1 = *(const float4*)(wp + (size_t)(i + 1) * 128);
        float4 w2 = *(const float4*)(wp + (size_t)(i + 2) * 128);
        float4 w3 = *(const float4*)(wp + (size_t)(i + 3) * 128);
        #pragma unroll
        for (int k = 0; k < 8; ++k) {
            float4 xv = *(const float4*)(xbase + (size_t)k * K + i);   // wave-broadcast
            acc[k].x += xv.x * w0.x + xv.y * w1.x + xv.z * w2.x + xv.w * w3.x;
            acc[k].y += xv.x * w0.y + xv.y * w1.y + xv.z * w2.y + xv.w * w3.y;
            acc[k].z += xv.x * w0.z + xv.y * w1.z + xv.z * w2.z + xv.w * w3.z;
            acc[k].w += xv.x * w0.w + xv.y * w1.w + xv.z * w2.w + xv.w * w3.w;
        }
    }
    #pragma unroll
    for (int k = 0; k < 8; ++k) {
        int n = n0 + ns * 8 + k;
        if (n < NNODE) *(float4*)(osel + (size_t)n * 128 + ccol) = acc[k];
    }
}

// ---------------- fused online-softmax GAT layer 1 (H=8, C=16) ----------------
__global__ __launch_bounds__(256) void fused1(const int* __restrict__ base,
                                              const int2* __restrict__ se,
                                              const float* __restrict__ xl,
                                              const float* __restrict__ xr,
                                              const float* __restrict__ w1e,
                                              const float* __restrict__ att1,
                                              const float* __restrict__ b1,
                                              float* __restrict__ h1) {
    int t = threadIdx.x;
    int wv = t >> 6, ln = t & 63;
    int half = ln >> 5, sub = ln & 31;
    int n = blockIdx.x * 4 + wv;
    int ch = sub * 4;
    float4 xrv = *(const float4*)(xr + (size_t)n * 128 + ch);
    float4 wev = *(const float4*)(w1e + ch);
    float4 atv = *(const float4*)(att1 + ch);
    int i0 = base[n], i1 = base[n + 1];
    float m = -1e30f, den = 0.f;
    float4 o = make_float4(0.f, 0.f, 0.f, 0.f);
    int i = i0 + half;
    if (i < i1) {
        int2 r = se[i];
        float4 xv = *(const float4*)(xl + (size_t)r.x * 128 + ch);
        float a = __int_as_float(r.y);
        for (i += 2; i < i1; i += 2) {
            int2 rn = se[i];
            float4 nxv = *(const float4*)(xl + (size_t)rn.x * 128 + ch);
            float na = __int_as_float(rn.y);
            float part = lrelu(fmaf(a, wev.x, xv.x + xrv.x)) * atv.x
                       + lrelu(fmaf(a, wev.y, xv.y + xrv.y)) * atv.y
                       + lrelu(fmaf(a, wev.z, xv.z + xrv.z)) * atv.z
                       + lrelu(fmaf(a, wev.w, xv.w + xrv.w)) * atv.w;
            part += __shfl_xor(part, 1, 64);
            part += __shfl_xor(part, 2, 64);
            float mn = fmaxf(m, part);
            float sc = __expf(m - mn);
            float p  = __expf(part - mn);
            den = den * sc + p;
            o.x = o.x * sc + p * xv.x;
            o.y = o.y * sc + p * xv.y;
            o.z = o.z * sc + p * xv.z;
            o.w = o.w * sc + p * xv.w;
            m = mn;
            xv = nxv; a = na;
        }
        float part = lrelu(fmaf(a, wev.x, xv.x + xrv.x)) * atv.x
                   + lrelu(fmaf(a, wev.y, xv.y + xrv.y)) * atv.y
                   + lrelu(fmaf(a, wev.z, xv.z + xrv.z)) * atv.z
                   + lrelu(fmaf(a, wev.w, xv.w + xrv.w)) * atv.w;
        part += __shfl_xor(part, 1, 64);
        part += __shfl_xor(part, 2, 64);
        float mn = fmaxf(m, part);
        float sc = __expf(m - mn);
        float p  = __expf(part - mn);
        den = den * sc + p;
        o.x = o.x * sc + p * xv.x;
        o.y = o.y * sc + p * xv.y;
        o.z = o.z * sc + p * xv.z;
        o.w = o.w * sc + p * xv.w;
        m = mn;
    }
    float m2   = __shfl_xor(m, 32, 64);
    float den2 = __shfl_xor(den, 32, 64);
    float4 o2;
    o2.x = __shfl_xor(o.x, 32, 64);
    o2.y = __shfl_xor(o.y, 32, 64);
    o2.z = __shfl_xor(o.z, 32, 64);
    o2.w = __shfl_xor(o.w, 32, 64);
    float mn = fmaxf(m, m2);
    float s1 = __expf(m - mn), s2 = __expf(m2 - mn);
    den = den * s1 + den2 * s2;
    float inv = 1.f / (den + 1e-16f);
    if (half == 0) {
        float4 bv = *(const float4*)(b1 + ch);
        float4 res;
        res.x = fmaxf((o.x * s1 + o2.x * s2) * inv + bv.x, 0.f);
        res.y = fmaxf((o.y * s1 + o2.y * s2) * inv + bv.y, 0.f);
        res.z = fmaxf((o.z * s1 + o2.z * s2) * inv + bv.z, 0.f);
        res.w = fmaxf((o.w * s1 + o2.w * s2) * inv + bv.w, 0.f);
        *(float4*)(h1 + (size_t)n * 128 + ch) = res;
    }
}

// ---------------- fused online-softmax GAT layer 2 (H=2, C=64, mean) ----------------
__global__ __launch_bounds__(256) void fused2(const int* __restrict__ base,
                                              const int2* __restrict__ se,
                                              const float* __restrict__ xl,
                                              const float* __restrict__ xr,
                                              const float* __restrict__ w2e,
                                              const float* __restrict__ att2,
                                              const float* __restrict__ b2,
                                              float* __restrict__ h2) {
    int t = threadIdx.x;
    int wv = t >> 6, ln = t & 63;
    int half = ln >> 5, sub = ln & 31;
    int n = blockIdx.x * 4 + wv;
    int ch = sub * 4;
    float4 xrv = *(const float4*)(xr + (size_t)n * 128 + ch);
    float4 wev = *(const float4*)(w2e + ch);
    float4 atv = *(const float4*)(att2 + ch);
    int i0 = base[n], i1 = base[n + 1];
    float m = -1e30f, den = 0.f;
    float4 o = make_float4(0.f, 0.f, 0.f, 0.f);
    int i = i0 + half;
    if (i < i1) {
        int2 r = se[i];
        float4 xv = *(const float4*)(xl + (size_t)r.x * 128 + ch);
        float a = __int_as_float(r.y);
        for (i += 2; i < i1; i += 2) {
            int2 rn = se[i];
            float4 nxv = *(const float4*)(xl + (size_t)rn.x * 128 + ch);
            float na = __int_as_float(rn.y);
            float part = lrelu(fmaf(a, wev.x, xv.x + xrv.x)) * atv.x
                       + lrelu(fmaf(a, wev.y, xv.y + xrv.y)) * atv.y
                       + lrelu(fmaf(a, wev.z, xv.z + xrv.z)) * atv.z
                       + lrelu(fmaf(a, wev.w, xv.w + xrv.w)) * atv.w;
            part += __shfl_xor(part, 1, 64);
            part += __shfl_xor(part, 2, 64);
            part += __shfl_xor(part, 4, 64);
            part += __shfl_xor(part, 8, 64);
            float mn = fmaxf(m, part);
            float sc = __expf(m - mn);
            float p  = __expf(part - mn);
            den = den * sc + p;
            o.x = o.x * sc + p * xv.x;
            o.y = o.y * sc + p * xv.y;
            o.z = o.z * sc + p * xv.z;
            o.w = o.w * sc + p * xv.w;
            m = mn;
            xv = nxv; a = na;
        }
        float part = lrelu(fmaf(a, wev.x, xv.x + xrv.x)) * atv.x
                   + lrelu(fmaf(a, wev.y, xv.y + xrv.y)) * atv.y
                   + lrelu(fmaf(a, wev.z, xv.z + xrv.z)) * atv.z
                   + lrelu(fmaf(a, wev.w, xv.w + xrv.w)) * atv.w;
        part += __shfl_xor(part, 1, 64);
        part += __shfl_xor(part, 2, 64);
        part += __shfl_xor(part, 4, 64);
        part += __shfl_xor(part, 8, 64);
        float mn = fmaxf(m, part);
        float sc = __expf(m - mn);
        float p  = __expf(part - mn);
        den = den * sc + p;
        o.x = o.x * sc + p * xv.x;
        o.y = o.y * sc + p * xv.y;
        o.z = o.z * sc + p * xv.z;
        o.w = o.w * sc + p * xv.w;
        m = mn;
    }
    float m2   = __shfl_xor(m, 32, 64);
    float den2 = __shfl_xor(den, 32, 64);
    float4 o2;
    o2.x = __shfl_xor(o.x, 32, 64);
    o2.y = __shfl_xor(o.y, 32, 64);
    o2.z = __shfl_xor(o.z, 32, 64);
    o2.w = __shfl_xor(o.w, 32, 64);
    float mn = fmaxf(m, m2);
    float s1 = __expf(m - mn), s2 = __expf(m2 - mn);
    den = den * s1 + den2 * s2;
    float inv = 1.f / (den + 1e-16f);
    float4 v;
    v.x = (o.x * s1 + o2.x * s2) * inv;
    v.y = (o.y * s1 + o2.y * s2) * inv;
    v.z = (o.z * s1 + o2.z * s2) * inv;
    v.w = (o.w * s1 + o2.w * s2) * inv;
    float4 u;
    u.x = __shfl_xor(v.x, 16, 64);
    u.y = __shfl_xor(v.y, 16, 64);
    u.z = __shfl_xor(v.z, 16, 64);
    u.w = __shfl_xor(v.w, 16, 64);
    if (half == 0 && sub < 16) {
        float4 bv = *(const float4*)(b2 + ch);
        float4 res;
        res.x = fmaxf(0.5f * (v.x + u.x) + bv.x, 0.f);
        res.y = fmaxf(0.5f * (v.y + u.y) + bv.y, 0.f);
        res.z = fmaxf(0.5f * (v.z + u.z) + bv.z, 0.f);
        res.w = fmaxf(0.5f * (v.w + u.w) + bv.w, 0.f);
        *(float4*)(h2 + (size_t)n * 64 + ch) = res;
    }
}

// ---------------- classifier: one wave (64 lanes) per node ----------------
__global__ __launch_bounds__(256) void classifier(const float* __restrict__ h2,
                                                  const float* __restrict__ wc,
                                                  const float* __restrict__ bc,
                                                  const float* __restrict__ lng,
                                                  const float* __restrict__ lnb,
                                                  const float* __restrict__ wr,
                                                  const float* __restrict__ br,
                                                  const float* __restrict__ lrg,
                                                  const float* __restrict__ lrb,
                                                  float* __restrict__ out) {
    __shared__ float rowA[4][64];
    __shared__ float rowB[4][64];
    int t = threadIdx.x;
    int wv = t >> 6, ln = t & 63;
    int n = blockIdx.x * 4 + wv;
    rowA[wv][ln] = h2[(size_t)n * 64 + ln];
    __syncthreads();
    float acc = bc[ln];
    #pragma unroll 8
    for (int i = 0; i < 64; ++i) acc += rowA[wv][i] * wc[i * 64 + ln];
    float mu = wsum64(acc) * (1.f / 64.f);
    float dv = acc - mu;
    float var = wsum64(dv * dv) * (1.f / 64.f);
    float y = dv * rsqrtf(var + 1e-5f) * lng[ln] + lnb[ln];
    float g1 = gelu_exact(y);
    rowB[wv][ln] = g1;
    __syncthreads();
    float acc2 = br[ln];
    #pragma unroll 8
    for (int i = 0; i < 64; ++i) acc2 += rowB[wv][i] * wr[i * 64 + ln];
    float mu2 = wsum64(acc2) * (1.f / 64.f);
    float dv2 = acc2 - mu2;
    float var2 = wsum64(dv2 * dv2) * (1.f / 64.f);
    float y2 = dv2 * rsqrtf(var2 + 1e-5f) * lrg[ln] + lrb[ln];
    float g2 = gelu_exact(y2);
    out[(size_t)n * 64 + ln] = g1 + g2;
}

extern "C" void kernel_launch(void* const* d_in, const int* in_sizes, int n_in,
                              void* d_out, int out_size, void* d_ws, size_t ws_size,
                              hipStream_t stream) {
    const float* x    = (const float*)d_in[0];
    const int*   ei   = (const int*)d_in[1];
    const float* ea   = (const float*)d_in[2];
    const float* w1l  = (const float*)d_in[3];
    const float* w1r  = (const float*)d_in[4];
    const float* w1e  = (const float*)d_in[5];
    const float* att1 = (const float*)d_in[6];
    const float* b1   = (const float*)d_in[7];
    const float* w2l  = (const float*)d_in[8];
    const float* w2r  = (const float*)d_in[9];
    const float* w2e  = (const float*)d_in[10];
    const float* att2 = (const float*)d_in[11];
    const float* b2   = (const float*)d_in[12];
    const float* wc   = (const float*)d_in[13];
    const float* bc   = (const float*)d_in[14];
    const float* lng  = (const float*)d_in[15];
    const float* lnb  = (const float*)d_in[16];
    const float* wr   = (const float*)d_in[17];
    const float* br   = (const float*)d_in[18];
    const float* lrg  = (const float*)d_in[19];
    const float* lrb  = (const float*)d_in[20];

    float* ws = (float*)d_ws;
    const size_t N128 = (size_t)NNODE * 128;
    float* xl = ws;
    float* xr = xl + N128;
    float* h1 = xr + N128;
    float* h2 = h1 + N128;
    int2*  se      = (int2*)(h2 + (size_t)NNODE * 64);   // NEDGE (8B aligned)
    int*   deg     = (int*)(se + NEDGE);
    int*   partial = deg + NNODE;
    int*   base    = partial + NNODE;         // NNODE+1
    int*   cursor  = base + NNODE + 1;
    int*   bsum    = cursor + NNODE;          // 256
    int*   boff    = bsum + 256;              // 256

    const int EB  = NEDGE / 256;              // 3125
    const int NBX = (NNODE + 31) / 32;        // 1563
    const int NB4 = NNODE / 4;                // 12500

    // ---- CSR build (dst-sorted) ----
    fill_u32<<<NBLK_SCAN, 256, 0, stream>>>((unsigned*)deg, 0u, NNODE);
    build_deg<<<EB, 256, 0, stream>>>(ei, deg);
    scan1<<<NBLK_SCAN, 256, 0, stream>>>(deg, partial, bsum);
    scan2<<<1, 256, 0, stream>>>(bsum, boff);
    scan3<<<NBLK_SCAN, 256, 0, stream>>>(partial, boff, base, cursor);
    scatter_edges<<<EB, 256, 0, stream>>>(ei, ea, cursor, se);

    // ---- layer 1 ----
    node_xform<64><<<NBX, 256, 0, stream>>>(x, w1l, w1r, xl, xr);
    fused1<<<NB4, 256, 0, stream>>>(base, se, xl, xr, w1e, att1, b1, h1);

    // ---- layer 2 ----
    node_xform<128><<<NBX, 256, 0, stream>>>(h1, w2l, w2r, xl, xr);
    fused2<<<NB4, 256, 0, stream>>>(base, se, xl, xr, w2e, att2, b2, h2);

    // ---- classifier ----
    classifier<<<NB4, 256, 0, stream>>>(h2, wc, bc, lng, lnb, wr, br, lrg, lrb,
                                        (float*)d_out);
}